// Round 1
// baseline (444.877 us; speedup 1.0000x reference)
//
#include <hip/hip_runtime.h>
#include <math.h>

#define NB 4
#define NC 128
#define NN 4096
#define ND 16

constexpr int TM = 64;   // m-tile (kv positions per iteration)
constexpr int TN = 64;   // n-tile (query rows per block)

// ---------------------------------------------------------------------------
// Kernel 1: fused Q/K/V projection (1x1 convs). Grid: B*64 blocks, 256 thr.
// Q[b][n][j] = (wq[j,:]·x[b,:,n] + bq[j]) * (1/sqrt(C))   (scale folded in)
// K[b][n][j] =  wk[j,:]·x[b,:,n] + bk[j]
// V[b][n][c] =  wv[c,:]·x[b,:,n] + bv[c]
// ---------------------------------------------------------------------------
__global__ __launch_bounds__(256) void proj_kernel(
    const float* __restrict__ x,
    const float* __restrict__ wq, const float* __restrict__ bq,
    const float* __restrict__ wk, const float* __restrict__ bk,
    const float* __restrict__ wv, const float* __restrict__ bv,
    float* __restrict__ Q, float* __restrict__ K, float* __restrict__ V)
{
    __shared__ float xs[NC][64];     // 32 KB: x tile [c][n]
    __shared__ float wch[160][32];   // 20 KB: weight chunk (rows: 16 q, 16 k, 128 v)
    __shared__ float bl[160];

    const int t  = threadIdx.x;
    const int b  = blockIdx.x >> 6;
    const int n0 = (blockIdx.x & 63) << 6;

    // stage x tile (coalesced: 64 consecutive floats per c-row)
    const float* xb = x + (size_t)b * NC * NN + n0;
    for (int idx = t; idx < NC * 64; idx += 256) {
        int c = idx >> 6, n = idx & 63;
        xs[c][n] = xb[(size_t)c * NN + n];
    }
    if (t < 16)        bl[t] = bq[t];
    else if (t < 32)   bl[t] = bk[t - 16];
    else if (t < 160)  bl[t] = bv[t - 32];
    __syncthreads();

    const int n  = t & 63;
    const int og = t >> 6;           // 0..3, 40 output rows each (wave-uniform)

    float acc[40];
#pragma unroll
    for (int i = 0; i < 40; ++i) acc[i] = bl[og * 40 + i];

    for (int cb = 0; cb < NC; cb += 32) {
        __syncthreads();   // protect wch from previous chunk's readers
        for (int idx = t; idx < 160 * 32; idx += 256) {
            int o = idx >> 5, cc = idx & 31;
            const float* src = (o < 16) ? (wq + o * NC)
                             : (o < 32) ? (wk + (o - 16) * NC)
                                        : (wv + (o - 32) * NC);
            wch[o][cc] = src[cb + cc];
        }
        __syncthreads();
#pragma unroll
        for (int c0 = 0; c0 < 32; c0 += 4) {
            const int c = cb + c0;
            const float x0 = xs[c][n],   x1 = xs[c+1][n];
            const float x2 = xs[c+2][n], x3 = xs[c+3][n];
#pragma unroll
            for (int i = 0; i < 40; ++i) {
                const float4 w4 = *(const float4*)&wch[og * 40 + i][c0];
                acc[i] += w4.x * x0 + w4.y * x1 + w4.z * x2 + w4.w * x3;
            }
        }
    }

    const float qscale = 1.0f / sqrtf((float)NC);
    const size_t row = (size_t)b * NN + n0 + n;
#pragma unroll
    for (int i = 0; i < 40; ++i) {
        const int o = og * 40 + i;
        const float v = acc[i];
        if (o < 16)      Q[row * ND + o]        = v * qscale;
        else if (o < 32) K[row * ND + (o - 16)] = v;
        else             V[row * NC + (o - 32)] = v;
    }
}

// ---------------------------------------------------------------------------
// Kernel 2: flash attention, fp32. Grid: B*64 blocks (64 q-rows each), 512 thr.
// out[b][c][n] = gamma * (sum_m softmax_m(q_n·k_m) * V[m][c]) + x[b][c][n]
// ---------------------------------------------------------------------------
__global__ __launch_bounds__(512) void attn_kernel(
    const float* __restrict__ Q, const float* __restrict__ K,
    const float* __restrict__ V, const float* __restrict__ x,
    const float* __restrict__ gammap, float* __restrict__ out)
{
    __shared__ float ks[TM][ND];      // 4 KB
    __shared__ float vs[TM][NC];      // 32 KB
    __shared__ float ps[TN][68];      // 17.4 KB (stride 68 -> conflict-free)
    __shared__ float redmax[8][TN];   // 2 KB
    __shared__ float redsum[8][TN];   // 2 KB
    __shared__ float rs[TN];
    __shared__ float ls[TN];

    const int t  = threadIdx.x;
    const int b  = blockIdx.x >> 6;
    const int n0 = (blockIdx.x & 63) << 6;

    // S-phase mapping: row sn, wave smg owns m = smg*8 + 0..7 (K reads uniform)
    const int sn  = t & 63;
    const int smg = t >> 6;
    // PV mapping: rows pnp+16j (j<4), cols pcg*4+i (i<4)
    const int pnp = t & 15;
    const int pcg = t >> 4;

    // q row into registers (already scaled by 1/sqrt(C))
    float qreg[ND];
    {
        const float4* qp = (const float4*)(Q + ((size_t)b * NN + n0 + sn) * ND);
        const float4 a0 = qp[0], a1 = qp[1], a2 = qp[2], a3 = qp[3];
        qreg[0]=a0.x;  qreg[1]=a0.y;  qreg[2]=a0.z;  qreg[3]=a0.w;
        qreg[4]=a1.x;  qreg[5]=a1.y;  qreg[6]=a1.z;  qreg[7]=a1.w;
        qreg[8]=a2.x;  qreg[9]=a2.y;  qreg[10]=a2.z; qreg[11]=a2.w;
        qreg[12]=a3.x; qreg[13]=a3.y; qreg[14]=a3.z; qreg[15]=a3.w;
    }

    float mrun = -3.402823466e38f, lrun = 0.0f;
    float o_acc[4][4];
#pragma unroll
    for (int j = 0; j < 4; ++j)
#pragma unroll
        for (int i = 0; i < 4; ++i) o_acc[j][i] = 0.0f;

    for (int m0 = 0; m0 < NN; m0 += TM) {
        // ---- stage K (64x16) and V (64x128) tiles ----
        if (t < 256) {
            const float4* ksrc = (const float4*)(K + ((size_t)b * NN + m0) * ND);
            ((float4*)ks)[t] = ksrc[t];
        }
        {
            const float4* vsrc = (const float4*)(V + ((size_t)b * NN + m0) * NC);
            float4* vdst = (float4*)vs;
#pragma unroll
            for (int i = 0; i < 4; ++i) vdst[t + 512 * i] = vsrc[t + 512 * i];
        }
        __syncthreads();

        // ---- scores: s[mm] = q_sn · k_(smg*8+mm)  (K rows wave-uniform) ----
        float s[8];
#pragma unroll
        for (int mm = 0; mm < 8; ++mm) {
            const int m = smg * 8 + mm;
            const float4* kr = (const float4*)&ks[m][0];
            float a = 0.0f;
#pragma unroll
            for (int jj = 0; jj < 4; ++jj) {
                const float4 k4 = kr[jj];
                a += k4.x * qreg[4*jj]   + k4.y * qreg[4*jj+1]
                   + k4.z * qreg[4*jj+2] + k4.w * qreg[4*jj+3];
            }
            s[mm] = a;
        }
        float lmax = s[0];
#pragma unroll
        for (int mm = 1; mm < 8; ++mm) lmax = fmaxf(lmax, s[mm]);
        redmax[smg][sn] = lmax;
        __syncthreads();

        float tmax = redmax[0][sn];
#pragma unroll
        for (int w = 1; w < 8; ++w) tmax = fmaxf(tmax, redmax[w][sn]);
        const float mnew = fmaxf(mrun, tmax);
        const float r = __expf(mrun - mnew);
        float p[8];
        float lsum = 0.0f;
#pragma unroll
        for (int mm = 0; mm < 8; ++mm) {
            p[mm] = __expf(s[mm] - mnew);
            lsum += p[mm];
        }
        *(float4*)&ps[sn][smg * 8]     = make_float4(p[0], p[1], p[2], p[3]);
        *(float4*)&ps[sn][smg * 8 + 4] = make_float4(p[4], p[5], p[6], p[7]);
        redsum[smg][sn] = lsum;
        if (smg == 0) rs[sn] = r;
        mrun = mnew;
        __syncthreads();

        float tsum = 0.0f;
#pragma unroll
        for (int w = 0; w < 8; ++w) tsum += redsum[w][sn];
        lrun = lrun * r + tsum;

        // ---- PV accumulate: o[j][i] += P[n_j][m] * V[m][c_i] ----
        float rr[4];
#pragma unroll
        for (int j = 0; j < 4; ++j) rr[j] = rs[pnp + 16 * j];
#pragma unroll
        for (int j = 0; j < 4; ++j)
#pragma unroll
            for (int i = 0; i < 4; ++i) o_acc[j][i] *= rr[j];

#pragma unroll 2
        for (int m = 0; m < TM; m += 4) {
            float pr[4][4];
#pragma unroll
            for (int j = 0; j < 4; ++j) {
                const float4 p4 = *(const float4*)&ps[pnp + 16 * j][m];
                pr[j][0] = p4.x; pr[j][1] = p4.y; pr[j][2] = p4.z; pr[j][3] = p4.w;
            }
#pragma unroll
            for (int mm = 0; mm < 4; ++mm) {
                const float4 v4 = *(const float4*)&vs[m + mm][pcg * 4];
#pragma unroll
                for (int j = 0; j < 4; ++j) {
                    o_acc[j][0] += pr[j][mm] * v4.x;
                    o_acc[j][1] += pr[j][mm] * v4.y;
                    o_acc[j][2] += pr[j][mm] * v4.z;
                    o_acc[j][3] += pr[j][mm] * v4.w;
                }
            }
        }
        __syncthreads();   // before next tile overwrites ks/vs/ps
    }

    if (smg == 0) ls[sn] = lrun;
    __syncthreads();

    const float g = gammap[0];
#pragma unroll
    for (int j = 0; j < 4; ++j) {
        const int nn = pnp + 16 * j;
        const float linv = 1.0f / ls[nn];
#pragma unroll
        for (int i = 0; i < 4; ++i) {
            const int c = pcg * 4 + i;
            const size_t idx = ((size_t)b * NC + c) * NN + n0 + nn;
            out[idx] = g * (o_acc[j][i] * linv) + x[idx];
        }
    }
}

// ---------------------------------------------------------------------------
extern "C" void kernel_launch(void* const* d_in, const int* in_sizes, int n_in,
                              void* d_out, int out_size, void* d_ws, size_t ws_size,
                              hipStream_t stream)
{
    const float* x  = (const float*)d_in[0];
    const float* wq = (const float*)d_in[1];
    const float* bq = (const float*)d_in[2];
    const float* wk = (const float*)d_in[3];
    const float* bk = (const float*)d_in[4];
    const float* wv = (const float*)d_in[5];
    const float* bv = (const float*)d_in[6];
    const float* gm = (const float*)d_in[7];
    float* out = (float*)d_out;

    float* Q = (float*)d_ws;                    // [B][N][16]
    float* K = Q + (size_t)NB * NN * ND;        // [B][N][16]
    float* V = K + (size_t)NB * NN * ND;        // [B][N][128]

    hipLaunchKernelGGL(proj_kernel, dim3(NB * 64), dim3(256), 0, stream,
                       x, wq, bq, wk, bk, wv, bv, Q, K, V);
    hipLaunchKernelGGL(attn_kernel, dim3(NB * 64), dim3(512), 0, stream,
                       Q, K, V, x, gm, out);
}

// Round 2
// 286.142 us; speedup vs baseline: 1.5547x; 1.5547x over previous
//
#include <hip/hip_runtime.h>
#include <math.h>

#define NB 4
#define NC 128
#define NN 4096
#define ND 16

constexpr int KV = 64;   // kv tile
constexpr int TN = 64;   // q rows per attn block

typedef short s16x8 __attribute__((ext_vector_type(8)));
typedef float f32x4 __attribute__((ext_vector_type(4)));

__device__ inline unsigned short f2b(float f) {
    union { float f; unsigned int u; } c; c.f = f;
    unsigned int u = c.u;
    return (unsigned short)((u + 0x7fffu + ((u >> 16) & 1u)) >> 16);  // RNE
}

// ---------------------------------------------------------------------------
// Kernel 1: fused Q/K/V projection. Grid: B*128 blocks (n-tile 32), 256 thr.
// Q fp32 [b][n][16] (scale folded), K fp32 [b][n][16], Vt bf16 [b][c][n].
// ---------------------------------------------------------------------------
__global__ __launch_bounds__(256) void proj_kernel(
    const float* __restrict__ x,
    const float* __restrict__ wq, const float* __restrict__ bq,
    const float* __restrict__ wk, const float* __restrict__ bk,
    const float* __restrict__ wv, const float* __restrict__ bv,
    float* __restrict__ Q, float* __restrict__ K, unsigned short* __restrict__ Vt)
{
    __shared__ float xs[NC][32];     // 16 KB
    __shared__ float wch[160][32];   // 20 KB
    __shared__ float bl[160];

    const int t  = threadIdx.x;
    const int b  = blockIdx.x >> 7;
    const int n0 = (blockIdx.x & 127) << 5;

    const float* xb = x + (size_t)b * NC * NN + n0;
    for (int idx = t; idx < NC * 32; idx += 256) {
        int c = idx >> 5, n = idx & 31;
        xs[c][n] = xb[(size_t)c * NN + n];
    }
    if (t < 16)        bl[t] = bq[t];
    else if (t < 32)   bl[t] = bk[t - 16];
    else if (t < 160)  bl[t] = bv[t - 32];
    __syncthreads();

    const int n  = t & 31;
    const int og = t >> 5;           // 0..7, 20 outputs each

    float acc[20];
#pragma unroll
    for (int i = 0; i < 20; ++i) acc[i] = bl[og * 20 + i];

    for (int cb = 0; cb < NC; cb += 32) {
        __syncthreads();
        for (int idx = t; idx < 160 * 32; idx += 256) {
            int o = idx >> 5, cc = idx & 31;
            const float* src = (o < 16) ? (wq + o * NC)
                             : (o < 32) ? (wk + (o - 16) * NC)
                                        : (wv + (o - 32) * NC);
            wch[o][cc] = src[cb + cc];
        }
        __syncthreads();
#pragma unroll
        for (int c0 = 0; c0 < 32; c0 += 4) {
            const float x0 = xs[cb + c0][n],     x1 = xs[cb + c0 + 1][n];
            const float x2 = xs[cb + c0 + 2][n], x3 = xs[cb + c0 + 3][n];
#pragma unroll
            for (int i = 0; i < 20; ++i) {
                const float4 w4 = *(const float4*)&wch[og * 20 + i][c0];
                acc[i] += w4.x * x0 + w4.y * x1 + w4.z * x2 + w4.w * x3;
            }
        }
    }

    const float qscale = 1.0f / sqrtf((float)NC);
    const size_t row = (size_t)b * NN + n0 + n;
#pragma unroll
    for (int i = 0; i < 20; ++i) {
        const int o = og * 20 + i;
        const float v = acc[i];
        if (o < 16)      Q[row * ND + o]        = v * qscale;
        else if (o < 32) K[row * ND + (o - 16)] = v;
        else             Vt[((size_t)b * NC + (o - 32)) * NN + n0 + n] = f2b(v);
    }
}

// ---------------------------------------------------------------------------
// Kernel 2: flash attention. fp32 S-phase + bf16 MFMA PV.
// Grid: B*64 blocks (64 q-rows each), 512 threads (8 waves).
// ---------------------------------------------------------------------------
__global__ __launch_bounds__(512) void attn_kernel(
    const float* __restrict__ Q, const float* __restrict__ K,
    const unsigned short* __restrict__ Vt, const float* __restrict__ x,
    const float* __restrict__ gammap, float* __restrict__ out)
{
    __shared__ float ks[KV][ND];                 // 4 KB (fp32 K tile)
    __shared__ unsigned short vsw[NC * KV];      // 16 KB bf16 [c][m], XOR-swizzled
    __shared__ unsigned short psw[TN * KV];      // 8 KB  bf16 [n][m], XOR-swizzled
    __shared__ float redmax[8][TN];              // 2 KB
    __shared__ float redsum[8][TN];              // 2 KB
    __shared__ float rs[TN];
    __shared__ float ls[TN];                     // 1/l at end
    __shared__ float os[64 * 68];                // 17.4 KB epilogue staging

    const int t    = threadIdx.x;
    const int lane = t & 63;
    const int b    = blockIdx.x >> 6;
    const int n0   = (blockIdx.x & 63) << 6;

    // S-phase mapping: row sn (=lane), wave smg owns m = smg*8 + 0..7
    const int sn  = t & 63;
    const int smg = t >> 6;
    // PV mapping: wave w -> row block rb (16 rows), col half chh (64 cols)
    const int w   = t >> 6;
    const int rb  = w & 3;
    const int chh = w >> 2;

    float qreg[ND];
    {
        const float4* qp = (const float4*)(Q + ((size_t)b * NN + n0 + sn) * ND);
        const float4 a0 = qp[0], a1 = qp[1], a2 = qp[2], a3 = qp[3];
        qreg[0]=a0.x;  qreg[1]=a0.y;  qreg[2]=a0.z;  qreg[3]=a0.w;
        qreg[4]=a1.x;  qreg[5]=a1.y;  qreg[6]=a1.z;  qreg[7]=a1.w;
        qreg[8]=a2.x;  qreg[9]=a2.y;  qreg[10]=a2.z; qreg[11]=a2.w;
        qreg[12]=a3.x; qreg[13]=a3.y; qreg[14]=a3.z; qreg[15]=a3.w;
    }

    float mrun = -3.402823466e38f, lrun = 0.0f;
    f32x4 acc[4];
#pragma unroll
    for (int cb = 0; cb < 4; ++cb) acc[cb] = (f32x4){0.f, 0.f, 0.f, 0.f};

    for (int m0 = 0; m0 < NN; m0 += KV) {
        __syncthreads();   // bar A: protect restage vs prev PV reads

        // ---- stage K (fp32) and Vt (bf16, swizzled) ----
        if (t < 256) {
            const int row = t >> 2, q4 = t & 3;
            *(float4*)&ks[row][q4 * 4] =
                *(const float4*)&K[((size_t)b * NN + m0 + row) * ND + q4 * 4];
        }
#pragma unroll
        for (int i = 0; i < 2; ++i) {
            const int idx = t + 512 * i;
            const int c = idx >> 3, ch = idx & 7;
            const s16x8 vv = *(const s16x8*)&Vt[((size_t)b * NC + c) * NN + m0 + ch * 8];
            *(s16x8*)&vsw[c * 64 + ((ch ^ (c & 7)) << 3)] = vv;
        }
        __syncthreads();   // bar B

        // ---- scores (fp32): s[mm] = q_sn · k_(smg*8+mm) ----
        float s[8];
#pragma unroll
        for (int mm = 0; mm < 8; ++mm) {
            const float4* kr = (const float4*)&ks[smg * 8 + mm][0];
            float a = 0.0f;
#pragma unroll
            for (int jj = 0; jj < 4; ++jj) {
                const float4 k4 = kr[jj];
                a += k4.x * qreg[4*jj]   + k4.y * qreg[4*jj+1]
                   + k4.z * qreg[4*jj+2] + k4.w * qreg[4*jj+3];
            }
            s[mm] = a;
        }
        float lmax = s[0];
#pragma unroll
        for (int mm = 1; mm < 8; ++mm) lmax = fmaxf(lmax, s[mm]);
        redmax[smg][sn] = lmax;
        __syncthreads();   // bar C

        float tmax = redmax[0][sn];
#pragma unroll
        for (int ww = 1; ww < 8; ++ww) tmax = fmaxf(tmax, redmax[ww][sn]);
        const float mnew = fmaxf(mrun, tmax);
        const float r = __expf(mrun - mnew);
        float lsum = 0.0f;
        s16x8 pv;
#pragma unroll
        for (int mm = 0; mm < 8; ++mm) {
            const float p = __expf(s[mm] - mnew);
            lsum += p;
            pv[mm] = (short)f2b(p);
        }
        *(s16x8*)&psw[sn * 64 + ((smg ^ (sn & 7)) << 3)] = pv;
        redsum[smg][sn] = lsum;
        if (smg == 0) rs[sn] = r;
        mrun = mnew;
        __syncthreads();   // bar D

        float tsum = 0.0f;
#pragma unroll
        for (int ww = 0; ww < 8; ++ww) tsum += redsum[ww][sn];
        lrun = lrun * r + tsum;

        // ---- rescale accumulators by r per output row ----
        float rv[4];
#pragma unroll
        for (int j = 0; j < 4; ++j) rv[j] = rs[rb * 16 + ((lane >> 4) << 2) + j];
#pragma unroll
        for (int cb = 0; cb < 4; ++cb)
#pragma unroll
            for (int j = 0; j < 4; ++j) acc[cb][j] *= rv[j];

        // ---- PV via MFMA: D[n][c] += P[n][m] * V[m][c] ----
#pragma unroll
        for (int kb = 0; kb < 2; ++kb) {
            const int arow = rb * 16 + (lane & 15);
            const int ach  = (kb * 4 + (lane >> 4)) ^ (arow & 7);
            const s16x8 af = *(const s16x8*)&psw[arow * 64 + (ach << 3)];
#pragma unroll
            for (int cb = 0; cb < 4; ++cb) {
                const int c   = chh * 64 + cb * 16 + (lane & 15);
                const int vch = (kb * 4 + (lane >> 4)) ^ (c & 7);
                const s16x8 bf = *(const s16x8*)&vsw[c * 64 + (vch << 3)];
                acc[cb] = __builtin_amdgcn_mfma_f32_16x16x32_bf16(af, bf, acc[cb], 0, 0, 0);
            }
        }
    }

    if (t < 64) ls[t] = 1.0f / lrun;
    __syncthreads();

    const float g = gammap[0];
#pragma unroll
    for (int h = 0; h < 2; ++h) {
        if (chh == h) {
#pragma unroll
            for (int j = 0; j < 4; ++j) {
                const int nloc = rb * 16 + ((lane >> 4) << 2) + j;
                const float linv = ls[nloc];
#pragma unroll
                for (int cb = 0; cb < 4; ++cb)
                    os[(cb * 16 + (lane & 15)) * 68 + nloc] = acc[cb][j] * linv;
            }
        }
        __syncthreads();
        {
            const int cl = t >> 3, nc8 = (t & 7) * 8;
            const size_t gbase = ((size_t)b * NC + h * 64 + cl) * NN + n0 + nc8;
            const float4 o0 = *(const float4*)&os[cl * 68 + nc8];
            const float4 o1 = *(const float4*)&os[cl * 68 + nc8 + 4];
            const float4 x0 = *(const float4*)&x[gbase];
            const float4 x1 = *(const float4*)&x[gbase + 4];
            float4 r0, r1;
            r0.x = g * o0.x + x0.x; r0.y = g * o0.y + x0.y;
            r0.z = g * o0.z + x0.z; r0.w = g * o0.w + x0.w;
            r1.x = g * o1.x + x1.x; r1.y = g * o1.y + x1.y;
            r1.z = g * o1.z + x1.z; r1.w = g * o1.w + x1.w;
            *(float4*)&out[gbase]     = r0;
            *(float4*)&out[gbase + 4] = r1;
        }
        __syncthreads();
    }
}

// ---------------------------------------------------------------------------
extern "C" void kernel_launch(void* const* d_in, const int* in_sizes, int n_in,
                              void* d_out, int out_size, void* d_ws, size_t ws_size,
                              hipStream_t stream)
{
    const float* x  = (const float*)d_in[0];
    const float* wq = (const float*)d_in[1];
    const float* bq = (const float*)d_in[2];
    const float* wk = (const float*)d_in[3];
    const float* bk = (const float*)d_in[4];
    const float* wv = (const float*)d_in[5];
    const float* bv = (const float*)d_in[6];
    const float* gm = (const float*)d_in[7];
    float* out = (float*)d_out;

    float* Q = (float*)d_ws;                          // [B][N][16] fp32
    float* K = Q + (size_t)NB * NN * ND;              // [B][N][16] fp32
    unsigned short* Vt = (unsigned short*)(K + (size_t)NB * NN * ND);  // [B][C][N] bf16

    hipLaunchKernelGGL(proj_kernel, dim3(NB * 128), dim3(256), 0, stream,
                       x, wq, bq, wk, bk, wv, bv, Q, K, Vt);
    hipLaunchKernelGGL(attn_kernel, dim3(NB * 64), dim3(512), 0, stream,
                       Q, K, Vt, x, gm, out);
}

// Round 3
// 156.861 us; speedup vs baseline: 2.8361x; 1.8242x over previous
//
#include <hip/hip_runtime.h>
#include <hip/hip_bf16.h>
#include <math.h>

#define NB 4
#define NC 128
#define NN 4096
#define ND 16

typedef short s16x8 __attribute__((ext_vector_type(8)));
typedef float f32x4 __attribute__((ext_vector_type(4)));
typedef unsigned int u32;

extern "C" __device__ float __ocml_native_exp2_f32(float);

__device__ __forceinline__ unsigned short f2b(float f) {
    __hip_bfloat16 h = __float2bfloat16(f);
    return *reinterpret_cast<unsigned short*>(&h);
}
__device__ __forceinline__ u32 f2b2(float lo, float hi) {
    __hip_bfloat162 h2 = __float22bfloat162_rn(make_float2(lo, hi));
    return *reinterpret_cast<u32*>(&h2);
}
__device__ __forceinline__ void gll16(const unsigned short* src, unsigned short* ldsdst) {
    __builtin_amdgcn_global_load_lds((const __attribute__((address_space(1))) u32*)src,
                                     (__attribute__((address_space(3))) u32*)ldsdst, 16, 0, 0);
}

// ---------------------------------------------------------------------------
// Kernel 1: Q/K/V projection as a bf16 MFMA GEMM.
// Grid: B*64 blocks (64-pixel tiles), 256 thr (4 waves).
// Outputs: Qb bf16 [b][n][16] (x log2e/sqrt(C) folded), Kb bf16 [b][n][16],
//          Vt bf16 [b][c][n].
// ---------------------------------------------------------------------------
__global__ __launch_bounds__(256) void proj_kernel(
    const float* __restrict__ x,
    const float* __restrict__ wq, const float* __restrict__ bq,
    const float* __restrict__ wk, const float* __restrict__ bk,
    const float* __restrict__ wv, const float* __restrict__ bv,
    unsigned short* __restrict__ Qb, unsigned short* __restrict__ Kb,
    unsigned short* __restrict__ Vt)
{
    __shared__ unsigned short xsw[64 * 128];   // [px][c] swizzled, 16 KB
    __shared__ unsigned short wsw[160 * 128];  // [o][c]  swizzled, 40 KB
    __shared__ float bl[160];

    const int t  = threadIdx.x;
    const int b  = blockIdx.x >> 6;
    const int n0 = (blockIdx.x & 63) << 6;

    // stage x tile -> bf16, transposed [px][c], chunk-XOR swizzle
#pragma unroll
    for (int p = 0; p < 8; ++p) {
        const int idx = (p * 256 + t) * 4;      // over 64px*128c
        const int c = idx >> 6, px0 = idx & 63;
        const float4 v4 = *(const float4*)&x[((size_t)(b * NC + c)) * NN + n0 + px0];
#pragma unroll
        for (int j = 0; j < 4; ++j) {
            const int px = px0 + j;
            xsw[px * 128 + (((c >> 3) ^ (px & 15)) << 3) + (c & 7)] = f2b((&v4.x)[j]);
        }
    }
    // stage weights -> bf16, [o][c], chunk-XOR swizzle
#pragma unroll
    for (int p = 0; p < 20; ++p) {
        const int idx = (p * 256 + t) * 4;      // over 160o*128c
        const int o = idx >> 7, c0 = idx & 127;
        const float* src = (o < 16) ? (wq + o * NC)
                         : (o < 32) ? (wk + (o - 16) * NC)
                                    : (wv + (o - 32) * NC);
        const float4 v4 = *(const float4*)&src[c0];
#pragma unroll
        for (int j = 0; j < 4; ++j) {
            const int c = c0 + j;
            wsw[o * 128 + (((c >> 3) ^ (o & 15)) << 3) + (c & 7)] = f2b((&v4.x)[j]);
        }
    }
    if (t < 160) bl[t] = (t < 16) ? bq[t] : (t < 32) ? bk[t - 16] : bv[t - 32];
    __syncthreads();

    const int lane = t & 63, w = t >> 6;
    const int l = lane & 15, h = lane >> 4;
    const int pxt = w;                      // wave's 16-px tile

    s16x8 af[4];
#pragma unroll
    for (int ks = 0; ks < 4; ++ks) {
        const int px = pxt * 16 + l;
        af[ks] = *(const s16x8*)&xsw[px * 128 + ((((ks * 4) + h) ^ (px & 15)) << 3)];
    }

    const float qscale = 1.4426950408889634f / sqrtf(128.0f);  // log2(e)/sqrt(C)

#pragma unroll
    for (int ot = 0; ot < 10; ++ot) {
        f32x4 acc = (f32x4){0.f, 0.f, 0.f, 0.f};
        const int o = ot * 16 + l;
#pragma unroll
        for (int ks = 0; ks < 4; ++ks) {
            const s16x8 bf = *(const s16x8*)&wsw[o * 128 + ((((ks * 4) + h) ^ l) << 3)];
            acc = __builtin_amdgcn_mfma_f32_16x16x32_bf16(af[ks], bf, acc, 0, 0, 0);
        }
        const float bias = bl[o];
        if (ot == 0) {
#pragma unroll
            for (int r = 0; r < 4; ++r) {
                const int px = pxt * 16 + h * 4 + r;
                Qb[((size_t)b * NN + n0 + px) * ND + l] = f2b((acc[r] + bias) * qscale);
            }
        } else if (ot == 1) {
#pragma unroll
            for (int r = 0; r < 4; ++r) {
                const int px = pxt * 16 + h * 4 + r;
                Kb[((size_t)b * NN + n0 + px) * ND + l] = f2b(acc[r] + bias);
            }
        } else {
            const int c = ot * 16 + l - 32;
            uint2 pk;
            pk.x = f2b2(acc[0] + bias, acc[1] + bias);
            pk.y = f2b2(acc[2] + bias, acc[3] + bias);
            const int px0 = pxt * 16 + h * 4;
            *(uint2*)&Vt[((size_t)b * NC + c) * NN + n0 + px0] = pk;
        }
    }
}

// ---------------------------------------------------------------------------
// Kernel 2: flash attention, all-MFMA, lane-local softmax state.
// Grid: 512 blocks (32 q-rows each), 256 thr (4 waves: nt in {0,1} x chalf).
// One __syncthreads per kv-tile; K/V double-buffered, prefetched 1 tile ahead.
// ---------------------------------------------------------------------------
__global__ __launch_bounds__(256) void attn_kernel(
    const unsigned short* __restrict__ Qb, const unsigned short* __restrict__ Kb,
    const unsigned short* __restrict__ Vt, const float* __restrict__ x,
    const float* __restrict__ gammap, float* __restrict__ out)
{
    __shared__ unsigned short vsw[2][128 * 64];   // 32 KB [c][m-slot] swizzled
    __shared__ unsigned short ksh[2][64 * 24];    // 6 KB  [m][d], 48B rows
    __shared__ unsigned short psw[4][16 * 64];    // 8 KB  per-wave [n][m] swizzled

    const int t    = threadIdx.x;
    const int lane = t & 63, w = t >> 6;
    const int l = lane & 15, h = lane >> 4;
    const int nt = w >> 1, ch = w & 1;

    // bijective XCD-aware mapping: each XCD pair serves one batch b
    const int bid = blockIdx.x;
    const int r_ = bid >> 8, s_ = bid & 255, xcd = s_ & 7, cu = s_ >> 3;
    const int b = xcd >> 1;
    const int tile = cu + ((xcd & 1) << 5) + (r_ << 6);
    const int n0 = tile << 5;

    // Q B-fragment (col n = l, k = d; zero-pad d>=16)
    s16x8 qf = {0, 0, 0, 0, 0, 0, 0, 0};
    if (h < 2) qf = *(const s16x8*)&Qb[((size_t)b * NN + n0 + nt * 16 + l) * ND + h * 8];

    // V staging geometry (per wave: rows c = w*32..w*32+31, 4 x 1KB gll)
    const int vch = (lane & 7) ^ (lane >> 3);          // pre-swizzled source chunk
    // K staging geometry (thread-level: 8B each)
    const int km = t >> 2, kp = t & 3;

    float mrun = -1e30f, lrun = 0.0f;
    f32x4 acc[4];
#pragma unroll
    for (int ct = 0; ct < 4; ++ct) acc[ct] = (f32x4){0.f, 0.f, 0.f, 0.f};

    // ---- prologue: stage tile 0, prefetch K(1) ----
#pragma unroll
    for (int i = 0; i < 4; ++i) {
        const int c = w * 32 + i * 8 + (lane >> 3);
        gll16(&Vt[((size_t)b * NC + c) * NN + 0 + vch * 8],
              (unsigned short*)((char*)&vsw[0][0] + w * 4096 + i * 1024));
    }
    uint2 kreg = *(const uint2*)&Kb[((size_t)b * NN + 0 + km) * ND + kp * 4];
    *(uint2*)&ksh[0][km * 24 + kp * 4] = kreg;
    kreg = *(const uint2*)&Kb[((size_t)b * NN + 64 + km) * ND + kp * 4];
    __syncthreads();

    int cur = 0;
    for (int it = 0; it < 64; ++it) {
        const int m0n = ((it + 1) & 63) << 6;
        // ---- prefetch next tile into buf[cur^1] ----
#pragma unroll
        for (int i = 0; i < 4; ++i) {
            const int c = w * 32 + i * 8 + (lane >> 3);
            gll16(&Vt[((size_t)b * NC + c) * NN + m0n + vch * 8],
                  (unsigned short*)((char*)&vsw[cur ^ 1][0] + w * 4096 + i * 1024));
        }
        *(uint2*)&ksh[cur ^ 1][km * 24 + kp * 4] = kreg;
        kreg = *(const uint2*)&Kb[((size_t)b * NN + (((it + 2) & 63) << 6) + km) * ND + kp * 4];

        // ---- S = K.Q^T via MFMA: D[m][n], col n = l (lane-local), rows m ----
        f32x4 sacc[4];
#pragma unroll
        for (int mt = 0; mt < 4; ++mt) {
            s16x8 afk = {0, 0, 0, 0, 0, 0, 0, 0};
            if (h < 2) afk = *(const s16x8*)&ksh[cur][(mt * 16 + l) * 24 + h * 8];
            sacc[mt] = __builtin_amdgcn_mfma_f32_16x16x32_bf16(
                afk, qf, (f32x4){0.f, 0.f, 0.f, 0.f}, 0, 0, 0);
        }

        // ---- online softmax over m (in-lane 16 values + cross-h shfl) ----
        float pmax = sacc[0][0];
#pragma unroll
        for (int mt = 0; mt < 4; ++mt)
#pragma unroll
            for (int r = 0; r < 4; ++r) pmax = fmaxf(pmax, sacc[mt][r]);
        pmax = fmaxf(pmax, __shfl_xor(pmax, 16));
        pmax = fmaxf(pmax, __shfl_xor(pmax, 32));
        const float mnew = fmaxf(mrun, pmax);
        const float rr = __ocml_native_exp2_f32(mrun - mnew);

        float p[4][4];
        float lsum = 0.0f;
#pragma unroll
        for (int mt = 0; mt < 4; ++mt)
#pragma unroll
            for (int r = 0; r < 4; ++r) {
                p[mt][r] = __ocml_native_exp2_f32(sacc[mt][r] - mnew);
                lsum += p[mt][r];
            }
        lsum += __shfl_xor(lsum, 16);
        lsum += __shfl_xor(lsum, 32);
        lrun = lrun * rr + lsum;
        mrun = mnew;

        // rescale accumulators (r is lane-local: all acc share col n)
#pragma unroll
        for (int ct = 0; ct < 4; ++ct)
#pragma unroll
            for (int r = 0; r < 4; ++r) acc[ct][r] *= rr;

        // ---- P -> bf16 -> per-wave psw [n][m] swizzled ----
#pragma unroll
        for (int mt = 0; mt < 4; ++mt) {
            const int mch = mt * 2 + (h >> 1);
            const int base = l * 64 + ((mch ^ (l & 7)) << 3) + ((h & 1) << 2);
            *(u32*)&psw[w][base]     = f2b2(p[mt][0], p[mt][1]);
            *(u32*)&psw[w][base + 2] = f2b2(p[mt][2], p[mt][3]);
        }
        s16x8 pf[2];
#pragma unroll
        for (int kb = 0; kb < 2; ++kb)
            pf[kb] = *(const s16x8*)&psw[w][l * 64 + (((kb * 4 + h) ^ (l & 7)) << 3)];

        // ---- PV: D[c][n] += V[c][m] * P[m][n] ----
#pragma unroll
        for (int ct = 0; ct < 4; ++ct) {
            const int c = ch * 64 + ct * 16 + l;
#pragma unroll
            for (int kb = 0; kb < 2; ++kb) {
                const s16x8 vf = *(const s16x8*)&vsw[cur][c * 64 + ((((kb * 4) + h) ^ (c & 7)) << 3)];
                acc[ct] = __builtin_amdgcn_mfma_f32_16x16x32_bf16(vf, pf[kb], acc[ct], 0, 0, 0);
            }
        }
        __syncthreads();   // drains gll/K prefetch (own vmcnt) + protects buffers
        cur ^= 1;
    }

    // ---- epilogue: out = gamma * acc/l + x ----
    const float g = gammap[0];
    const float linv = 1.0f / lrun;
    const int n = n0 + nt * 16 + l;
#pragma unroll
    for (int ct = 0; ct < 4; ++ct)
#pragma unroll
        for (int r = 0; r < 4; ++r) {
            const int c = ch * 64 + ct * 16 + h * 4 + r;
            const size_t idx = ((size_t)b * NC + c) * NN + n;
            out[idx] = g * (acc[ct][r] * linv) + x[idx];
        }
}

// ---------------------------------------------------------------------------
extern "C" void kernel_launch(void* const* d_in, const int* in_sizes, int n_in,
                              void* d_out, int out_size, void* d_ws, size_t ws_size,
                              hipStream_t stream)
{
    const float* x  = (const float*)d_in[0];
    const float* wq = (const float*)d_in[1];
    const float* bq = (const float*)d_in[2];
    const float* wk = (const float*)d_in[3];
    const float* bk = (const float*)d_in[4];
    const float* wv = (const float*)d_in[5];
    const float* bv = (const float*)d_in[6];
    const float* gm = (const float*)d_in[7];
    float* out = (float*)d_out;

    unsigned short* Qb = (unsigned short*)d_ws;              // [B][N][16] bf16
    unsigned short* Kb = Qb + (size_t)NB * NN * ND;          // [B][N][16] bf16
    unsigned short* Vt = Kb + (size_t)NB * NN * ND;          // [B][C][N] bf16

    hipLaunchKernelGGL(proj_kernel, dim3(NB * 64), dim3(256), 0, stream,
                       x, wq, bq, wk, bk, wv, bv, Qb, Kb, Vt);
    hipLaunchKernelGGL(attn_kernel, dim3(512), dim3(256), 0, stream,
                       Qb, Kb, Vt, x, gm, out);
}